// Round 8
// baseline (91.532 us; speedup 1.0000x reference)
//
#include <hip/hip_runtime.h>
#include <hip/hip_bf16.h>
#include <math.h>

// SetConvEncoder via separable Gaussian + split-bf16 MFMA.
//  out[b][ch][gy][gx] = sum_n EX[n][gx]*EY[n][gy]*y4[n][ch]
//  = GEMM C[m=4*gy+ch][gx] += sum_k A[k][m]*B[k][n],  A=YT=EY*y4, B=EX
// R7 bench: passed (split-bf16 + layout verified). Total 102.9->89.4us.
//  Iteration-structure-invariant inference: main kernel ~31us (vs 7-10 predicted).
//  Harness floor: 40us fillBuffer poison of 256MiB d_ws inside timed region.
// R8 theory: 31us = barrier-exposed load latency at 2 blocks/CU (~150 VGPR under
//  bounds(256,2) -> 8 waves/CU; 2 barriers/chunk; xc/yc/mask loads on critical
//  path). Fix: bounds(256,4) + VGPR trim (drop coord hoists, per-j B frags),
//  KSPLIT 16 (1024 blocks -> 4/CU), and next-chunk register prefetch.
// k-slot layout: A and B panels use the SAME bijective (lane-group,j)->k map ->
//  HW k-permutations cancel; load-bearing: row/col=lane&15 symmetry + m89 C/D map.

typedef float f32x4 __attribute__((ext_vector_type(4)));
typedef short s16x8 __attribute__((ext_vector_type(8)));

constexpr int BB = 8, NN = 2048, GH = 128, GW = 128;
constexpr int GY_TILE = 16;              // block covers 16 gy -> M = 64 rows
constexpr int OUTSZ = BB * 4 * GH * GW;  // 524288 floats per partial slice

// split v into bf16 hi + bf16 lo (lo = bf16(v - float(hi))); pack two k-adjacent
// values into one u32 per panel (low u16 = k0). Compiler emits v_cvt_pk_bf16_f32.
__device__ __forceinline__ void split2(float v0, float v1,
                                       unsigned& hi, unsigned& lo) {
    __hip_bfloat16 a = __float2bfloat16(v0);
    __hip_bfloat16 b = __float2bfloat16(v1);
    float fa = __bfloat162float(a), fb = __bfloat162float(b);
    __hip_bfloat16 ra = __float2bfloat16(v0 - fa);
    __hip_bfloat16 rb = __float2bfloat16(v1 - fb);
    unsigned short ua, ub, uc, ud;
    __builtin_memcpy(&ua, &a, 2);  __builtin_memcpy(&ub, &b, 2);
    __builtin_memcpy(&uc, &ra, 2); __builtin_memcpy(&ud, &rb, 2);
    hi = (unsigned)ua | ((unsigned)ub << 16);
    lo = (unsigned)uc | ((unsigned)ud << 16);
}

template <int KS, bool ATOMIC>
__global__ __launch_bounds__(256, 4) void setconv_mfma(
    const float* __restrict__ xc,    // [B,N,2]
    const float* __restrict__ yc,    // [B,N,3]
    const float* __restrict__ mask,  // [B,N]
    const float* __restrict__ logls, // [1]
    const float* __restrict__ grid,  // [H,W,2]
    float* __restrict__ dst)         // ATOMIC: out (zeroed); else partials [KS][OUTSZ]
{
    constexpr int NK  = NN / KS;     // ctx points per block
    constexpr int NCH = NK / 32;     // K-chunks of 32

    // frag-order panels: u32 slot s -> lane-row q=s>>2 (tile=q>>6, lane=q&63),
    // jp=s&3 (bf16 elems 2jp,2jp+1). One lane-row = 4 u32 = 16B = one s16x8 frag.
    __shared__ unsigned sA[2][4 * 64 * 4];   // [hi/lo][M=64 x K=32]  4 KB each
    __shared__ unsigned sB[2][8 * 64 * 4];   // [hi/lo][N=128 x K=32] 8 KB each

    const int ks  = blockIdx.x;
    const int gyt = blockIdx.y;
    const int b   = blockIdx.z;
    const int tid = threadIdx.x;
    const int l   = tid & 63;   // lane
    const int w   = tid >> 6;   // wave 0..3

    const float ls = __expf(logls[0]);
    const float cc = -0.72134752044f / (ls * ls);  // -0.5*log2(e)/ls^2

    // ---- staging decode (thread-constant) ----
    const int lane_s = tid >> 2;
    const int jp     = tid & 3;
    const int sb15   = lane_s & 15;            // n%16 (B) or m%16 (A)
    const int kg     = lane_s >> 4;            // k-group 0..3
    const int k0     = ((jp >> 1) << 4) | (kg << 2) | ((jp & 1) << 1); // even
    const int ch     = sb15 & 3;               // A: channel
    const int gyb    = sb15 >> 2;              // A: gy%4 base

    // wave tile: 2 m-tiles x 4 n-tiles of 16x16
    const int mtb = (w & 1) * 2;
    const int ntb = (w >> 1) * 4;

    f32x4 acc[2][4];
#pragma unroll
    for (int i = 0; i < 2; ++i)
#pragma unroll
        for (int j = 0; j < 4; ++j) acc[i][j] = (f32x4){0.f, 0.f, 0.f, 0.f};

    const int nb0 = b * NN + ks * NK;

    // ---- prefetch chunk 0 globals into registers ----
    int kb = nb0 + k0;
    float4 xy = *(const float4*)&xc[(size_t)kb * 2];  // x0,y0,x1,y1 (k0 even -> 16B aligned)
    float2 mk = *(const float2*)&mask[kb];
    float yv0 = 0.f, yv1 = 0.f;
    if (ch < 3) {
        yv0 = yc[(size_t)kb * 3 + ch];
        yv1 = yc[(size_t)(kb + 1) * 3 + ch];
    }

    for (int chn = 0; chn < NCH; ++chn) {
        const float y40 = (ch < 3) ? yv0 * mk.x : mk.x;
        const float y41 = (ch < 3) ? yv1 * mk.y : mk.y;

        __syncthreads();  // previous chunk's frag reads done

        // ---- stage B = EX (8 n-tiles): conflict-free consecutive-u32 writes ----
#pragma unroll
        for (int r = 0; r < 8; ++r) {
            float gxv = grid[(r * 16 + sb15) * 2 + 0];  // L1-resident reload
            float d0 = gxv - xy.x, d1 = gxv - xy.z;
            unsigned hi, lo;
            split2(exp2f(cc * d0 * d0), exp2f(cc * d1 * d1), hi, lo);
            sB[0][r * 256 + tid] = hi;
            sB[1][r * 256 + tid] = lo;
        }
        // ---- stage A = YT (4 m-tiles) ----
#pragma unroll
        for (int r = 0; r < 4; ++r) {
            float gyv = grid[(size_t)(gyt * GY_TILE + r * 4 + gyb) * GW * 2 + 1];
            float d0 = gyv - xy.y, d1 = gyv - xy.w;
            unsigned hi, lo;
            split2(exp2f(cc * d0 * d0) * y40, exp2f(cc * d1 * d1) * y41, hi, lo);
            sA[0][r * 256 + tid] = hi;
            sA[1][r * 256 + tid] = lo;
        }

        // ---- prefetch next chunk (hides under MFMA phase + barrier) ----
        if (chn + 1 < NCH) {
            kb = nb0 + (chn + 1) * 32 + k0;
            xy = *(const float4*)&xc[(size_t)kb * 2];
            mk = *(const float2*)&mask[kb];
            if (ch < 3) {
                yv0 = yc[(size_t)kb * 3 + ch];
                yv1 = yc[(size_t)(kb + 1) * 3 + ch];
            }
        }
        __syncthreads();

        // ---- fragments + 24 MFMAs (B frags loaded per-j to cut live VGPRs) ----
        const s16x8* pAh = (const s16x8*)sA[0];
        const s16x8* pAl = (const s16x8*)sA[1];
        const s16x8* pBh = (const s16x8*)sB[0];
        const s16x8* pBl = (const s16x8*)sB[1];
        s16x8 ah[2], al[2];
#pragma unroll
        for (int i = 0; i < 2; ++i) {
            ah[i] = pAh[(mtb + i) * 64 + l];
            al[i] = pAl[(mtb + i) * 64 + l];
        }
#pragma unroll
        for (int j = 0; j < 4; ++j) {
            s16x8 bh = pBh[(ntb + j) * 64 + l];
            s16x8 bl = pBl[(ntb + j) * 64 + l];
#pragma unroll
            for (int i = 0; i < 2; ++i) {
                acc[i][j] = __builtin_amdgcn_mfma_f32_16x16x32_bf16(
                    ah[i], bh, acc[i][j], 0, 0, 0);
                acc[i][j] = __builtin_amdgcn_mfma_f32_16x16x32_bf16(
                    ah[i], bl, acc[i][j], 0, 0, 0);
                acc[i][j] = __builtin_amdgcn_mfma_f32_16x16x32_bf16(
                    al[i], bh, acc[i][j], 0, 0, 0);
            }
        }
    }

    // ---- epilogue: C/D map col=l&15 (gx), row=(l>>4)*4+reg (m=4*gy+ch) ----
    const int colg = l & 15, rowg = l >> 4;
    float* slice = ATOMIC ? dst : dst + (size_t)ks * OUTSZ;
#pragma unroll
    for (int i = 0; i < 2; ++i) {
        const int gy = gyt * GY_TILE + (mtb + i) * 4 + rowg;
#pragma unroll
        for (int j = 0; j < 4; ++j) {
            const int gx = (ntb + j) * 16 + colg;
#pragma unroll
            for (int r = 0; r < 4; ++r) {  // r == channel
                const size_t off = (((size_t)(b * 4 + r)) * GH + gy) * GW + gx;
                if (ATOMIC) atomicAdd(&slice[off], acc[i][j][r]);
                else        slice[off] = acc[i][j][r];
            }
        }
    }
}

template <int KS>
__global__ __launch_bounds__(256, 8) void setconv_reduce(
    const float* __restrict__ pw,  // [KS][OUTSZ]
    float* __restrict__ out)       // [OUTSZ]
{
    const int n4 = OUTSZ / 4;
    const int stride = gridDim.x * 256;
    const float4* p = (const float4*)pw;
    for (int i = blockIdx.x * 256 + threadIdx.x; i < n4; i += stride) {
        float4 s = p[i];
#pragma unroll
        for (int k = 1; k < KS; ++k) {
            float4 v = p[(size_t)k * n4 + i];
            s.x += v.x; s.y += v.y; s.z += v.z; s.w += v.w;
        }
        ((float4*)out)[i] = s;
    }
}

extern "C" void kernel_launch(void* const* d_in, const int* in_sizes, int n_in,
                              void* d_out, int out_size, void* d_ws, size_t ws_size,
                              hipStream_t stream) {
    const float* xc    = (const float*)d_in[0];  // x_context [8,2048,2]
    const float* yc    = (const float*)d_in[1];  // y_context [8,2048,3]
    const float* mask  = (const float*)d_in[2];  // context_mask [8,2048]
    const float* logls = (const float*)d_in[3];  // log_lengthscale [1]
    const float* grid  = (const float*)d_in[4];  // grid [128,128,2]
    float* out = (float*)d_out;                  // [8,4,128,128]

    const size_t need16 = (size_t)16 * OUTSZ * sizeof(float);  // 32 MB
    const size_t need8  = (size_t)8  * OUTSZ * sizeof(float);  // 16 MB

    if (ws_size >= need16) {
        float* pw = (float*)d_ws;
        dim3 gdim(16, GH / GY_TILE, BB);  // 1024 blocks -> 4/CU, 16 waves/CU
        setconv_mfma<16, false><<<gdim, 256, 0, stream>>>(xc, yc, mask, logls,
                                                          grid, pw);
        setconv_reduce<16><<<dim3(512), 256, 0, stream>>>(pw, out);
    } else if (ws_size >= need8) {
        float* pw = (float*)d_ws;
        dim3 gdim(8, GH / GY_TILE, BB);   // 512 blocks
        setconv_mfma<8, false><<<gdim, 256, 0, stream>>>(xc, yc, mask, logls,
                                                         grid, pw);
        setconv_reduce<8><<<dim3(512), 256, 0, stream>>>(pw, out);
    } else {
        hipMemsetAsync(out, 0, (size_t)out_size * sizeof(float), stream);
        dim3 gdim(8, GH / GY_TILE, BB);
        setconv_mfma<8, true><<<gdim, 256, 0, stream>>>(xc, yc, mask, logls,
                                                        grid, out);
    }
}